// Round 5
// baseline (36476.358 us; speedup 1.0000x reference)
//
#include <hip/hip_runtime.h>
#include <stdint.h>

#define NB 64
#define NT 2048
#define ND 1024
#define NU 1024
#define FLAG_STRIDE 16  // flags 64B apart -> no shared-line convoy

typedef __attribute__((ext_vector_type(8))) short bf16x8;
typedef __attribute__((ext_vector_type(4))) float f32x4;
typedef unsigned long long u64;

__device__ __forceinline__ unsigned short f2bf(float f) {
  union { float f; unsigned u; } v; v.f = f;
  return (unsigned short)((v.u + 0x7FFFu + ((v.u >> 16) & 1u)) >> 16);
}

// ---------------- init: zero flag area + h double-buffer ----------------
__global__ void init_ws(unsigned* __restrict__ ws) {
  const int n = 4096 + 2 * NB * NU / 2;  // 16KB flags + 256KB bf16 h x2 (as u32 words)
  for (int i = blockIdx.x * blockDim.x + threadIdx.x; i < n; i += gridDim.x * blockDim.x)
    ws[i] = 0u;
}

// ---------------- xp = inputs @ W_x + b  (bf16 MFMA, 128x128 tile) ----------------
__launch_bounds__(256, 3)
__global__ void gemm_xp(const float* __restrict__ inp, const float* __restrict__ Wx,
                        const float* __restrict__ bias, float* __restrict__ xp,
                        int t0, int Tc) {
  __shared__ unsigned short As[128][56];
  __shared__ unsigned short Bs[128][56];

  const int tid = threadIdx.x;
  const int u0 = blockIdx.x * 128;
  const int m_base = blockIdx.y * 128;
  const int b = m_base / Tc;
  const int tc0 = m_base % Tc;
  const size_t arow0 = ((size_t)b * NT + t0 + tc0) * (size_t)ND;

  const int w = tid >> 6, lane = tid & 63;
  const int wr = w >> 1, wc = w & 1;
  const int l15 = lane & 15, lk = lane >> 4;
  const int srow = tid & 127;
  const int shalf = tid >> 7;

  f32x4 acc[4][4];
  #pragma unroll
  for (int i = 0; i < 4; ++i)
    #pragma unroll
    for (int j = 0; j < 4; ++j)
      acc[i][j] = (f32x4){0.f, 0.f, 0.f, 0.f};

  for (int k0 = 0; k0 < ND; k0 += 32) {
    __syncthreads();
    {
      const float* src = inp + arow0 + (size_t)srow * ND + k0 + shalf * 16;
      unsigned short tmp[16];
      #pragma unroll
      for (int i = 0; i < 16; i += 4) {
        float4 v = *(const float4*)(src + i);
        tmp[i + 0] = f2bf(v.x); tmp[i + 1] = f2bf(v.y);
        tmp[i + 2] = f2bf(v.z); tmp[i + 3] = f2bf(v.w);
      }
      #pragma unroll
      for (int h = 0; h < 2; ++h) {
        bf16x8 pv;
        #pragma unroll
        for (int j = 0; j < 8; ++j) pv[j] = (short)tmp[h * 8 + j];
        *(bf16x8*)&As[srow][shalf * 16 + h * 8] = pv;
      }
    }
    {
      const float* src = Wx + (size_t)(k0 + shalf * 16) * NU + u0 + srow;
      unsigned short tmp[16];
      #pragma unroll
      for (int i = 0; i < 16; ++i) tmp[i] = f2bf(src[(size_t)i * NU]);
      #pragma unroll
      for (int h = 0; h < 2; ++h) {
        bf16x8 pv;
        #pragma unroll
        for (int j = 0; j < 8; ++j) pv[j] = (short)tmp[h * 8 + j];
        *(bf16x8*)&Bs[srow][shalf * 16 + h * 8] = pv;
      }
    }
    __syncthreads();

    bf16x8 af[4], bfr[4];
    #pragma unroll
    for (int mf = 0; mf < 4; ++mf)
      af[mf] = *(const bf16x8*)&As[wr * 64 + mf * 16 + l15][lk * 8];
    #pragma unroll
    for (int nf = 0; nf < 4; ++nf)
      bfr[nf] = *(const bf16x8*)&Bs[wc * 64 + nf * 16 + l15][lk * 8];
    #pragma unroll
    for (int mf = 0; mf < 4; ++mf)
      #pragma unroll
      for (int nf = 0; nf < 4; ++nf)
        acc[mf][nf] = __builtin_amdgcn_mfma_f32_16x16x32_bf16(af[mf], bfr[nf], acc[mf][nf], 0, 0, 0);
  }

  #pragma unroll
  for (int nf = 0; nf < 4; ++nf) {
    const int col = u0 + wc * 64 + nf * 16 + l15;
    const float bv = bias[col];
    #pragma unroll
    for (int mf = 0; mf < 4; ++mf) {
      const int rbase = m_base + wr * 64 + mf * 16 + lk * 4;
      #pragma unroll
      for (int r = 0; r < 4; ++r)
        xp[(size_t)(rbase + r) * NU + col] = acc[mf][nf][r] + bv;
    }
  }
}

// ---------------- persistent recurrent scan: staggered groups, wave-autonomous ----------------
// 32 WGs x 512 threads. Wave = (group g = w>>1 owning rows [g*16,+16), col half ch = w&1).
// Wave owns cols [wid*32+ch*16, +16) with FULL K=1024: W_h slice in 128 VGPRs.
// Per step: poll group's 64 flags -> 64 u64 sc1 A-loads + 32 MFMA -> tanh ->
// packed u32 sc1 stores -> per-wave vmcnt(0) -> relaxed flag. No barriers, no LDS.
// The 4 groups are independent recurrences -> they stagger and hide each other's latency.
__launch_bounds__(512, 2)
__global__ void scan_kernel(const float* __restrict__ Wh, const float* __restrict__ xp,
                            unsigned short* __restrict__ hbuf, float* __restrict__ out,
                            unsigned* __restrict__ flags, int t0, int Tc) {
  const int tid = threadIdx.x;
  const int wid = blockIdx.x;        // 0..31
  const int lane = tid & 63;
  const int w = tid >> 6;            // 0..7
  const int g = w >> 1;              // batch group, rows [g*16, +16)
  const int ch = w & 1;
  const int col16 = wid * 32 + ch * 16;
  const int l15 = lane & 15, lk = lane >> 4;

  // ---- persistent W_h B-fragments: 32 x bf16x8 = 128 VGPR ----
  bf16x8 Bf[32];
  for (int kk = 0; kk < 32; ++kk) {
    bf16x8 v;
    #pragma unroll
    for (int j = 0; j < 8; ++j)
      v[j] = (short)f2bf(Wh[(size_t)(kk * 32 + lk * 8 + j) * NU + col16 + l15]);
    Bf[kk] = v;
  }

  const int rowA = g * 16 + l15;      // A-fragment row this lane reads
  const int rowC = g * 16 + lk * 4;   // C row base this lane writes

  unsigned* fown = flags + (size_t)(g * 64 + wid * 2 + ch) * FLAG_STRIDE;
  const unsigned* fpoll = flags + (size_t)(g * 64 + lane) * FLAG_STRIDE;

  for (int tc = 0; tc < Tc; ++tc) {
    const int t = t0 + tc;
    const unsigned short* hc = hbuf + (size_t)(t & 1) * (NB * NU);
    unsigned short* hn = hbuf + (size_t)((t + 1) & 1) * (NB * NU);

    // xp prefetch (independent of h) before the poll
    float xpv[4];
    #pragma unroll
    for (int r = 0; r < 4; ++r)
      xpv[r] = xp[((size_t)(rowC + r) * Tc + tc) * NU + col16 + l15];

    // ---- poll all 64 producer flags of this group (1 load/lane/round) ----
    if (t != 0) {
      const unsigned tgt = (unsigned)t;
      for (;;) {
        const unsigned fv =
            __hip_atomic_load(fpoll, __ATOMIC_RELAXED, __HIP_MEMORY_SCOPE_AGENT);
        if (__all((int)(fv >= tgt))) break;
        __builtin_amdgcn_s_sleep(1);
      }
      asm volatile("" ::: "memory");  // keep A-loads below the poll
    }

    // ---- full-K MFMA: A via pipelined sc1 u64 loads, B from VGPRs ----
    f32x4 accA = {0.f, 0.f, 0.f, 0.f}, accB = {0.f, 0.f, 0.f, 0.f};
    const unsigned short* abase = hc + (size_t)rowA * NU + lk * 8;
    #pragma unroll
    for (int kk = 0; kk < 32; kk += 2) {
      const u64* p0 = (const u64*)(abase + kk * 32);
      const u64* p1 = (const u64*)(abase + (kk + 1) * 32);
      const u64 a00 = __hip_atomic_load(p0,     __ATOMIC_RELAXED, __HIP_MEMORY_SCOPE_AGENT);
      const u64 a01 = __hip_atomic_load(p0 + 1, __ATOMIC_RELAXED, __HIP_MEMORY_SCOPE_AGENT);
      const u64 a10 = __hip_atomic_load(p1,     __ATOMIC_RELAXED, __HIP_MEMORY_SCOPE_AGENT);
      const u64 a11 = __hip_atomic_load(p1 + 1, __ATOMIC_RELAXED, __HIP_MEMORY_SCOPE_AGENT);
      union { u64 q[2]; bf16x8 v; } ua, ub;
      ua.q[0] = a00; ua.q[1] = a01;
      ub.q[0] = a10; ub.q[1] = a11;
      accA = __builtin_amdgcn_mfma_f32_16x16x32_bf16(ua.v, Bf[kk],     accA, 0, 0, 0);
      accB = __builtin_amdgcn_mfma_f32_16x16x32_bf16(ub.v, Bf[kk + 1], accB, 0, 0, 0);
    }
    const f32x4 z4 = accA + accB;

    // ---- epilogue: xp + tanh -> packed u32 sc1 stores ----
    #pragma unroll
    for (int r = 0; r < 4; ++r) {
      const float z = z4[r] + xpv[r];
      const float e = __expf(2.0f * z);
      const float hv = 1.0f - 2.0f / (e + 1.0f);   // tanh(z)
      if (t == NT - 1) out[(size_t)(rowC + r) * NU + col16 + l15] = hv;
      const unsigned mybf = f2bf(hv);
      const unsigned nb = (unsigned)__shfl_xor((int)mybf, 1);
      if (!(lane & 1)) {
        __hip_atomic_store((unsigned*)(hn + (size_t)(rowC + r) * NU + col16 + l15),
                           mybf | (nb << 16), __ATOMIC_RELAXED, __HIP_MEMORY_SCOPE_AGENT);
      }
    }

    // per-wave drain: this wave's h stores are at the coherence point, then flag
    asm volatile("s_waitcnt vmcnt(0)" ::: "memory");
    if (lane == 0)
      __hip_atomic_store(fown, (unsigned)(t + 1), __ATOMIC_RELAXED, __HIP_MEMORY_SCOPE_AGENT);
  }
}

extern "C" void kernel_launch(void* const* d_in, const int* in_sizes, int n_in,
                              void* d_out, int out_size, void* d_ws, size_t ws_size,
                              hipStream_t stream) {
  (void)in_sizes; (void)n_in; (void)out_size;
  const float* inp  = (const float*)d_in[0];
  const float* Wx   = (const float*)d_in[1];
  const float* Wh   = (const float*)d_in[2];
  const float* bias = (const float*)d_in[3];
  float* out = (float*)d_out;

  unsigned* flags = (unsigned*)d_ws;                                // 16 KB flag area
  unsigned short* hbuf = (unsigned short*)((char*)d_ws + 16384);    // 256 KB h double-buffer
  const size_t xp_off = 16384 + (size_t)2 * NB * NU * sizeof(unsigned short);
  float* xp = (float*)((char*)d_ws + xp_off);
  const size_t avail = (ws_size > xp_off) ? ws_size - xp_off : 0;

  int Tc = 128;
  for (int cand = NT; cand >= 128; cand >>= 1)
    if ((size_t)NB * (size_t)cand * NU * sizeof(float) <= avail) { Tc = cand; break; }

  init_ws<<<dim3(128), dim3(256), 0, stream>>>((unsigned*)d_ws);

  for (int t0 = 0; t0 < NT; t0 += Tc) {
    gemm_xp<<<dim3(8, (NB * Tc) / 128), dim3(256), 0, stream>>>(inp, Wx, bias, xp, t0, Tc);
    scan_kernel<<<dim3(32), dim3(512), 0, stream>>>(Wh, xp, hbuf, out, flags, t0, Tc);
  }
}

// Round 6
// 19877.437 us; speedup vs baseline: 1.8351x; 1.8351x over previous
//
#include <hip/hip_runtime.h>
#include <stdint.h>

#define NB 64
#define NT 2048
#define ND 1024
#define NU 1024
#define FLAG_STRIDE 16  // flags 64B apart -> no shared-line convoy

typedef __attribute__((ext_vector_type(8))) short bf16x8;
typedef __attribute__((ext_vector_type(4))) float f32x4;
typedef unsigned long long u64;

__device__ __forceinline__ unsigned short f2bf(float f) {
  union { float f; unsigned u; } v; v.f = f;
  return (unsigned short)((v.u + 0x7FFFu + ((v.u >> 16) & 1u)) >> 16);
}

// ---------------- init: zero flag area + h double-buffer ----------------
__global__ void init_ws(unsigned* __restrict__ ws) {
  const int n = 1024 + (2 * NB * NU) / 2;  // 4KB flags + 256KB bf16 h x2
  for (int i = blockIdx.x * blockDim.x + threadIdx.x; i < n; i += gridDim.x * blockDim.x)
    ws[i] = 0u;
}

// ---------------- xp = inputs @ W_x + b  (bf16 MFMA, 128x128 tile) ----------------
__launch_bounds__(256, 3)
__global__ void gemm_xp(const float* __restrict__ inp, const float* __restrict__ Wx,
                        const float* __restrict__ bias, float* __restrict__ xp,
                        int t0, int Tc) {
  __shared__ unsigned short As[128][56];
  __shared__ unsigned short Bs[128][56];

  const int tid = threadIdx.x;
  const int u0 = blockIdx.x * 128;
  const int m_base = blockIdx.y * 128;
  const int b = m_base / Tc;
  const int tc0 = m_base % Tc;
  const size_t arow0 = ((size_t)b * NT + t0 + tc0) * (size_t)ND;

  const int w = tid >> 6, lane = tid & 63;
  const int wr = w >> 1, wc = w & 1;
  const int l15 = lane & 15, lk = lane >> 4;
  const int srow = tid & 127;
  const int shalf = tid >> 7;

  f32x4 acc[4][4];
  #pragma unroll
  for (int i = 0; i < 4; ++i)
    #pragma unroll
    for (int j = 0; j < 4; ++j)
      acc[i][j] = (f32x4){0.f, 0.f, 0.f, 0.f};

  for (int k0 = 0; k0 < ND; k0 += 32) {
    __syncthreads();
    {
      const float* src = inp + arow0 + (size_t)srow * ND + k0 + shalf * 16;
      unsigned short tmp[16];
      #pragma unroll
      for (int i = 0; i < 16; i += 4) {
        float4 v = *(const float4*)(src + i);
        tmp[i + 0] = f2bf(v.x); tmp[i + 1] = f2bf(v.y);
        tmp[i + 2] = f2bf(v.z); tmp[i + 3] = f2bf(v.w);
      }
      #pragma unroll
      for (int h = 0; h < 2; ++h) {
        bf16x8 pv;
        #pragma unroll
        for (int j = 0; j < 8; ++j) pv[j] = (short)tmp[h * 8 + j];
        *(bf16x8*)&As[srow][shalf * 16 + h * 8] = pv;
      }
    }
    {
      const float* src = Wx + (size_t)(k0 + shalf * 16) * NU + u0 + srow;
      unsigned short tmp[16];
      #pragma unroll
      for (int i = 0; i < 16; ++i) tmp[i] = f2bf(src[(size_t)i * NU]);
      #pragma unroll
      for (int h = 0; h < 2; ++h) {
        bf16x8 pv;
        #pragma unroll
        for (int j = 0; j < 8; ++j) pv[j] = (short)tmp[h * 8 + j];
        *(bf16x8*)&Bs[srow][shalf * 16 + h * 8] = pv;
      }
    }
    __syncthreads();

    bf16x8 af[4], bfr[4];
    #pragma unroll
    for (int mf = 0; mf < 4; ++mf)
      af[mf] = *(const bf16x8*)&As[wr * 64 + mf * 16 + l15][lk * 8];
    #pragma unroll
    for (int nf = 0; nf < 4; ++nf)
      bfr[nf] = *(const bf16x8*)&Bs[wc * 64 + nf * 16 + l15][lk * 8];
    #pragma unroll
    for (int mf = 0; mf < 4; ++mf)
      #pragma unroll
      for (int nf = 0; nf < 4; ++nf)
        acc[mf][nf] = __builtin_amdgcn_mfma_f32_16x16x32_bf16(af[mf], bfr[nf], acc[mf][nf], 0, 0, 0);
  }

  #pragma unroll
  for (int nf = 0; nf < 4; ++nf) {
    const int col = u0 + wc * 64 + nf * 16 + l15;
    const float bv = bias[col];
    #pragma unroll
    for (int mf = 0; mf < 4; ++mf) {
      const int rbase = m_base + wr * 64 + mf * 16 + lk * 4;
      #pragma unroll
      for (int r = 0; r < 4; ++r)
        xp[(size_t)(rbase + r) * NU + col] = acc[mf][nf][r] + bv;
    }
  }
}

// ---------------- persistent recurrent scan, 16 WG x 512, flag-array sync ----------------
// WG owns 64 output columns. Wave (k4, m2): K-quarter [k4*256,+256), rows [m2*32,+32),
// all 64 cols (Bf[4][8] in 128 VGPRs). Per step: poll 4 producer flags of the K-quarter,
// sc1 u64 A-loads (one h copy per WG), 64 MFMA, LDS K-reduce, tanh, packed u32 stores,
// syncthreads (vmcnt0 drain), relaxed flag store. No RELEASE -> no per-step L2 writeback.
__launch_bounds__(512, 1)
__global__ void scan_kernel(const float* __restrict__ Wh, const float* __restrict__ xp,
                            unsigned short* __restrict__ hbuf, float* __restrict__ out,
                            unsigned* __restrict__ flags, int t0, int Tc) {
  __shared__ float Red[4][2][64][36];  // [k4][m2][col][row(+pad)] f32 partials (74 KB)

  const int tid = threadIdx.x;
  const int wid = blockIdx.x;   // 0..15
  const int col0 = wid * 64;
  const int lane = tid & 63;
  const int w = tid >> 6;       // 0..7
  const int k4 = w & 3;         // K-quarter: k in [k4*256, +256)
  const int m2 = w >> 2;        // M-half: rows [m2*32, +32)
  const int l15 = lane & 15;
  const int lk = lane >> 4;

  // ---- persistent W_h B-fragments: Bf[nf][kq] = 128 VGPR ----
  bf16x8 Bf[4][8];
  for (int nf = 0; nf < 4; ++nf)
    for (int kq = 0; kq < 8; ++kq) {
      const int col = col0 + nf * 16 + l15;
      bf16x8 v;
      #pragma unroll
      for (int j = 0; j < 8; ++j) {
        const int k = (k4 * 8 + kq) * 32 + lk * 8 + j;
        v[j] = (short)f2bf(Wh[(size_t)k * NU + col]);
      }
      Bf[nf][kq] = v;
    }

  // reduce/store mapping: thread -> (1 col, 8 rows)
  const int rcol = tid & 63;
  const int rgrp = tid >> 6;        // 0..7
  const int rrow = rgrp * 8;        // rows rrow..rrow+8
  const int rm = rgrp >> 2;         // m-half
  const int rlm = (rgrp & 3) * 8;   // row base within half

  // poll set: producers of cols [k4*256,+256) = WGs [k4*4, +4)
  const unsigned* fpoll = flags + (size_t)(k4 * 4 + (lane & 3)) * FLAG_STRIDE;
  unsigned* fown = flags + (size_t)wid * FLAG_STRIDE;

  for (int tc = 0; tc < Tc; ++tc) {
    const int t = t0 + tc;
    const unsigned short* hc = hbuf + (size_t)(t & 1) * (NB * NU);
    unsigned short* hn = hbuf + (size_t)((t + 1) & 1) * (NB * NU);

    // xp prefetch (independent of h) before the poll
    float xpv[8];
    #pragma unroll
    for (int r = 0; r < 8; ++r)
      xpv[r] = xp[((size_t)(rrow + r) * Tc + tc) * NU + col0 + rcol];

    // ---- poll the 4 producer flags of this wave's K-quarter ----
    if (t != 0) {
      const unsigned tgt = (unsigned)t;
      for (;;) {
        unsigned fv = tgt;
        if (lane < 4)
          fv = __hip_atomic_load(fpoll, __ATOMIC_RELAXED, __HIP_MEMORY_SCOPE_AGENT);
        if (__all((int)(fv >= tgt))) break;
        __builtin_amdgcn_s_sleep(1);
      }
      asm volatile("" ::: "memory");  // keep A-loads below the poll
    }

    // ---- MFMA: A (h_t) via sc1 u64 loads (one h copy per WG), B from VGPRs ----
    f32x4 acc[2][4];
    #pragma unroll
    for (int mf = 0; mf < 2; ++mf)
      #pragma unroll
      for (int nf = 0; nf < 4; ++nf)
        acc[mf][nf] = (f32x4){0.f, 0.f, 0.f, 0.f};

    #pragma unroll
    for (int kq = 0; kq < 8; ++kq) {
      #pragma unroll
      for (int mf = 0; mf < 2; ++mf) {
        const int row = m2 * 32 + mf * 16 + l15;
        const u64* p = (const u64*)(hc + (size_t)row * NU + (k4 * 8 + kq) * 32 + lk * 8);
        const u64 q0 = __hip_atomic_load(p,     __ATOMIC_RELAXED, __HIP_MEMORY_SCOPE_AGENT);
        const u64 q1 = __hip_atomic_load(p + 1, __ATOMIC_RELAXED, __HIP_MEMORY_SCOPE_AGENT);
        union { u64 q[2]; bf16x8 v; } u; u.q[0] = q0; u.q[1] = q1;
        #pragma unroll
        for (int nf = 0; nf < 4; ++nf)
          acc[mf][nf] = __builtin_amdgcn_mfma_f32_16x16x32_bf16(u.v, Bf[nf][kq], acc[mf][nf], 0, 0, 0);
      }
    }

    // write K-partials
    #pragma unroll
    for (int mf = 0; mf < 2; ++mf)
      #pragma unroll
      for (int nf = 0; nf < 4; ++nf)
        *(f32x4*)&Red[k4][m2][nf * 16 + l15][mf * 16 + lk * 4] = acc[mf][nf];
    __syncthreads();  // partials visible (also guards Red reuse from prev step)

    // ---- reduce + xp + tanh -> packed u32 sc1 stores (8 rows x 1 col per thread) ----
    {
      f32x4 sa = *(const f32x4*)&Red[0][rm][rcol][rlm];
      f32x4 sb = *(const f32x4*)&Red[0][rm][rcol][rlm + 4];
      #pragma unroll
      for (int q = 1; q < 4; ++q) {
        sa += *(const f32x4*)&Red[q][rm][rcol][rlm];
        sb += *(const f32x4*)&Red[q][rm][rcol][rlm + 4];
      }
      #pragma unroll
      for (int r = 0; r < 4; ++r) {
        const float z = sa[r] + xpv[r];
        const float e = __expf(2.0f * z);
        const float hv = 1.0f - 2.0f / (e + 1.0f);   // tanh(z)
        if (t == NT - 1) out[(size_t)(rrow + r) * NU + col0 + rcol] = hv;
        const unsigned mybf = f2bf(hv);
        const unsigned nb = (unsigned)__shfl_xor((int)mybf, 1);
        if (!(lane & 1))
          __hip_atomic_store((unsigned*)(hn + (size_t)(rrow + r) * NU + col0 + rcol),
                             mybf | (nb << 16), __ATOMIC_RELAXED, __HIP_MEMORY_SCOPE_AGENT);
      }
      #pragma unroll
      for (int r = 0; r < 4; ++r) {
        const float z = sb[r] + xpv[r + 4];
        const float e = __expf(2.0f * z);
        const float hv = 1.0f - 2.0f / (e + 1.0f);
        if (t == NT - 1) out[(size_t)(rrow + 4 + r) * NU + col0 + rcol] = hv;
        const unsigned mybf = f2bf(hv);
        const unsigned nb = (unsigned)__shfl_xor((int)mybf, 1);
        if (!(lane & 1))
          __hip_atomic_store((unsigned*)(hn + (size_t)(rrow + 4 + r) * NU + col0 + rcol),
                             mybf | (nb << 16), __ATOMIC_RELAXED, __HIP_MEMORY_SCOPE_AGENT);
      }
    }
    __syncthreads();  // vmcnt(0) drain in every wave: all h stores ACKed at coherence point

    if (tid == 0)     // relaxed is safe: data already at the coherence point
      __hip_atomic_store(fown, (unsigned)(t + 1), __ATOMIC_RELAXED, __HIP_MEMORY_SCOPE_AGENT);
  }
}

extern "C" void kernel_launch(void* const* d_in, const int* in_sizes, int n_in,
                              void* d_out, int out_size, void* d_ws, size_t ws_size,
                              hipStream_t stream) {
  (void)in_sizes; (void)n_in; (void)out_size;
  const float* inp  = (const float*)d_in[0];
  const float* Wx   = (const float*)d_in[1];
  const float* Wh   = (const float*)d_in[2];
  const float* bias = (const float*)d_in[3];
  float* out = (float*)d_out;

  unsigned* flags = (unsigned*)d_ws;                               // 4 KB flag area
  unsigned short* hbuf = (unsigned short*)((char*)d_ws + 4096);    // 256 KB h double-buffer
  const size_t xp_off = 4096 + (size_t)2 * NB * NU * sizeof(unsigned short);
  float* xp = (float*)((char*)d_ws + xp_off);
  const size_t avail = (ws_size > xp_off) ? ws_size - xp_off : 0;

  int Tc = 128;
  for (int cand = NT; cand >= 128; cand >>= 1)
    if ((size_t)NB * (size_t)cand * NU * sizeof(float) <= avail) { Tc = cand; break; }

  init_ws<<<dim3(128), dim3(256), 0, stream>>>((unsigned*)d_ws);

  for (int t0 = 0; t0 < NT; t0 += Tc) {
    gemm_xp<<<dim3(8, (NB * Tc) / 128), dim3(256), 0, stream>>>(inp, Wx, bias, xp, t0, Tc);
    scan_kernel<<<dim3(16), dim3(512), 0, stream>>>(Wh, xp, hbuf, out, flags, t0, Tc);
  }
}